// Round 20
// baseline (392.313 us; speedup 1.0000x reference)
//
#include <hip/hip_runtime.h>

#define NB 2
#define NN 4096
#define DIMD 512
#define PD 64
#define KNN 16
#define QB 8
#define CAP 192
#define CTRIG 52
#define RCAP 48
#define MROWS (NB*NN)       // 8192
#define FLOW_BLOCKS (MROWS/4)

typedef unsigned short ushort_t;

// ---------------- kernel 1: fused prep = flow (f64, LDS-staged W^T) + values GEMM ----------
// (r18/r19 verbatim)
__global__ __launch_bounds__(256)
void prep_kernel(const float* __restrict__ states, const float* __restrict__ positions,
                 const float* __restrict__ W_flow, const float* __restrict__ b_flow,
                 const float* __restrict__ W_val, const float* __restrict__ b_val,
                 float* __restrict__ out_np, float* __restrict__ out_fl,
                 float* __restrict__ npos_lo, float* __restrict__ p4t,
                 double* __restrict__ sq64, float* __restrict__ sqf,
                 float* __restrict__ values_ws)
{
    __shared__ __align__(16) unsigned char POOL[24832];
    const int t = threadIdx.x;

    if (blockIdx.x < FLOW_BLOCKS) {
        float (*s_lds)[DIMD] = (float(*)[DIMD])POOL;          // [4][512]  8192 B
        float (*wlds)[65]    = (float(*)[65])(POOL + 8192);   // [64][65] 16640 B
        const int row0 = blockIdx.x * 4;
        const float4* src = (const float4*)(states + (size_t)row0 * DIMD);
        float4* dst = (float4*)&s_lds[0][0];
        dst[t] = src[t];
        dst[t + 256] = src[t + 256];
        const int lr = t >> 6;
        const int p  = t & 63;
        const int row = row0 + lr;
        double a0 = 0.0, a1 = 0.0, a2 = 0.0, a3 = 0.0;
        for (int ph = 0; ph < 8; ++ph) {
            const int d0 = ph << 6;
            __syncthreads();
            #pragma unroll
            for (int i = 0; i < 4; ++i) {
                int slot = t + (i << 8);
                int r = slot >> 4, c = slot & 15;
                float4 wv = *(const float4*)(W_flow + (size_t)r * DIMD + d0 + (c << 2));
                wlds[(c<<2)+0][r] = wv.x;
                wlds[(c<<2)+1][r] = wv.y;
                wlds[(c<<2)+2][r] = wv.z;
                wlds[(c<<2)+3][r] = wv.w;
            }
            __syncthreads();
            #pragma unroll
            for (int sc = 0; sc < 4; ++sc) {
                const int dl = sc << 4;
                float4 s0 = *(const float4*)&s_lds[lr][d0 + dl + 0];
                float4 s1 = *(const float4*)&s_lds[lr][d0 + dl + 4];
                float4 s2 = *(const float4*)&s_lds[lr][d0 + dl + 8];
                float4 s3 = *(const float4*)&s_lds[lr][d0 + dl + 12];
                a0 += (double)s0.x * (double)wlds[dl+ 0][p];
                a1 += (double)s0.y * (double)wlds[dl+ 1][p];
                a2 += (double)s0.z * (double)wlds[dl+ 2][p];
                a3 += (double)s0.w * (double)wlds[dl+ 3][p];
                a0 += (double)s1.x * (double)wlds[dl+ 4][p];
                a1 += (double)s1.y * (double)wlds[dl+ 5][p];
                a2 += (double)s1.z * (double)wlds[dl+ 6][p];
                a3 += (double)s1.w * (double)wlds[dl+ 7][p];
                a0 += (double)s2.x * (double)wlds[dl+ 8][p];
                a1 += (double)s2.y * (double)wlds[dl+ 9][p];
                a2 += (double)s2.z * (double)wlds[dl+10][p];
                a3 += (double)s2.w * (double)wlds[dl+11][p];
                a0 += (double)s3.x * (double)wlds[dl+12][p];
                a1 += (double)s3.y * (double)wlds[dl+13][p];
                a2 += (double)s3.z * (double)wlds[dl+14][p];
                a3 += (double)s3.w * (double)wlds[dl+15][p];
            }
        }
        double acc = ((a0 + a1) + (a2 + a3)) + (double)b_flow[p];
        const size_t g = (size_t)row * PD + p;
        double np_ = (double)positions[g] + 0.1 * acc;
        float hi = (float)np_;
        float lo = (float)(np_ - (double)hi);
        out_fl[g]   = (float)acc;
        out_np[g]   = hi;
        npos_lo[g]  = lo;
        const int bb = row >> 12, n = row & (NN - 1);
        p4t[(((size_t)bb*16 + (p >> 2))*NN + n)*4 + (p & 3)] = hi;
        double s2 = np_ * np_;
        #pragma unroll
        for (int off = 32; off >= 1; off >>= 1) s2 += __shfl_xor(s2, off);
        if (p == 0) { sq64[row] = s2; sqf[row] = (float)s2; }
    } else {
        float (*As)[68] = (float(*)[68])POOL;              // 4352 B
        float (*Bs)[68] = (float(*)[68])(POOL + 4352);     // 4352 B
        const int idx = blockIdx.x - FLOW_BLOCKS;
        const int bn = idx & 7, bm = idx >> 3;
        const int lr  = t >> 2;
        const int lc4 = (t & 3) << 2;
        const int cr = (t >> 4) << 2;
        const int cc = (t & 15) << 2;
        float acc[4][4] = {};
        for (int k0 = 0; k0 < DIMD; k0 += 16) {
            float4 av = *(const float4*)(states + (size_t)(bm*64 + lr)*DIMD + k0 + lc4);
            float4 wv = *(const float4*)(W_val  + (size_t)(bn*64 + lr)*DIMD + k0 + lc4);
            __syncthreads();
            As[lc4+0][lr] = av.x; As[lc4+1][lr] = av.y; As[lc4+2][lr] = av.z; As[lc4+3][lr] = av.w;
            Bs[lc4+0][lr] = wv.x; Bs[lc4+1][lr] = wv.y; Bs[lc4+2][lr] = wv.z; Bs[lc4+3][lr] = wv.w;
            __syncthreads();
            #pragma unroll
            for (int kk = 0; kk < 16; ++kk) {
                float4 a  = *(const float4*)&As[kk][cr];
                float4 b4 = *(const float4*)&Bs[kk][cc];
                acc[0][0] += a.x*b4.x; acc[0][1] += a.x*b4.y; acc[0][2] += a.x*b4.z; acc[0][3] += a.x*b4.w;
                acc[1][0] += a.y*b4.x; acc[1][1] += a.y*b4.y; acc[1][2] += a.y*b4.z; acc[1][3] += a.y*b4.w;
                acc[2][0] += a.z*b4.x; acc[2][1] += a.z*b4.y; acc[2][2] += a.z*b4.z; acc[2][3] += a.z*b4.w;
                acc[3][0] += a.w*b4.x; acc[3][1] += a.w*b4.y; acc[3][2] += a.w*b4.z; acc[3][3] += a.w*b4.w;
            }
        }
        const int colb = bn*64 + cc;
        float4 bb = *(const float4*)(b_val + colb);
        #pragma unroll
        for (int i = 0; i < 4; ++i) {
            float4 o;
            o.x = acc[i][0] + bb.x;
            o.y = acc[i][1] + bb.y;
            o.z = acc[i][2] + bb.z;
            o.w = acc[i][3] + bb.w;
            *(float4*)(values_ws + (size_t)(bm*64 + cr + i)*DIMD + colb) = o;
        }
    }
}

// ---------------- kernel 2: half-split select (2048 blocks) + per-half exact top-16 --------
// Block = (b, query-group n0, candidate half). Wave w owns 512 cands (2 chunks x 256,
// r19's chunk body verbatim). Selection invariants unchanged (CAP 192 >= CTRIG 52 + 128).
// Per-half exact f64 top-16 written as (d2,idx) into ctx row dead space (disjoint slices).
__global__ __launch_bounds__(256, 4)
void dist_select(const float* __restrict__ nph, const float* __restrict__ npl,
                 const float4* __restrict__ p4t, const float* __restrict__ sqf,
                 const double* __restrict__ sq64, float* __restrict__ ctx)
{
    __shared__ __align__(16) unsigned char POOL[24576];
    __shared__ float    qstage[QB][68];
    __shared__ ushort_t rlist[QB][4][RCAP];
    __shared__ int      ccnt[QB][4];
    __shared__ int      rcnt[QB][4];

    // phase 1 aliases
    ushort_t (*sd16)[4][CAP]  = (ushort_t(*)[4][CAP])POOL;               // 12288
    ushort_t (*six16)[4][CAP] = (ushort_t(*)[4][CAP])(POOL + 12288);     // 12288
    // phase 2 aliases
    double (*umbd)[192] = (double(*)[192])POOL;                          // 12288
    int*    umbi        = (int*)(POOL + 12288);                          //  6144
    double (*qd64)[66]  = (double(*)[66])(POOL + 18432);                 //  4224

    const int tid  = threadIdx.x;
    const int w    = tid >> 6;        // segment id within half
    const int lane = tid & 63;
    const int b    = blockIdx.x >> 10;
    const int rem  = blockIdx.x & 1023;
    const int n0   = (rem >> 1) << 3;
    const int half = rem & 1;
    const int base = b * NN;

    if (tid < 32) ccnt[tid >> 2][tid & 3] = 0;
    if (tid < 128) {
        int row = tid >> 4, c4 = (tid & 15) << 2;
        *(float4*)&qstage[row][c4] = *(const float4*)(nph + (size_t)(base + n0 + row)*PD + c4);
    }
    __syncthreads();

    float sqq[QB], tv[QB];
    #pragma unroll
    for (int j = 0; j < QB; ++j) { sqq[j] = sqf[base + n0 + j]; tv[j] = 1e30f; }

    const float4* P4 = p4t + (size_t)b * 16 * NN;
    const int qbase = (half << 11) + (w << 9);   // half*2048 + wave*512

    #define APPEND1(J, DV, CI)                                                  \
        if ((DV) < tv[J]) {                                                     \
            int s_ = atomicAdd(&ccnt[J][w], 1);                                 \
            if (s_ < CAP) {                                                     \
                sd16[J][w][s_]  = (ushort_t)(__float_as_uint(DV) >> 16);        \
                six16[J][w][s_] = (ushort_t)(CI);                               \
            }                                                                   \
        }

    #define COMPACT1(J)                                                         \
        {                                                                       \
            int cnt0 = ccnt[J][w];                                              \
            if (cnt0 > CTRIG) {                                                 \
                if (cnt0 > CAP) cnt0 = CAP;                                     \
                ushort_t v0 = (lane       < cnt0) ? sd16[J][w][lane]       : (ushort_t)0xFFFF; \
                ushort_t v1 = (64 + lane  < cnt0) ? sd16[J][w][64 + lane]  : (ushort_t)0xFFFF; \
                ushort_t v2 = (128 + lane < cnt0) ? sd16[J][w][128 + lane] : (ushort_t)0xFFFF; \
                ushort_t i0 = (lane       < cnt0) ? six16[J][w][lane]       : (ushort_t)0; \
                ushort_t i1 = (64 + lane  < cnt0) ? six16[J][w][64 + lane]  : (ushort_t)0; \
                ushort_t i2 = (128 + lane < cnt0) ? six16[J][w][128 + lane] : (ushort_t)0; \
                unsigned lo_ = 0u, hi_ = 0x7F80u;                               \
                _Pragma("unroll 1")                                             \
                for (int it = 0; it < 16; ++it) {                               \
                    unsigned mid = (lo_ + hi_) >> 1;                            \
                    int cnt = __popcll(__ballot((unsigned)v0 < mid))            \
                            + __popcll(__ballot((unsigned)v1 < mid))            \
                            + __popcll(__ballot((unsigned)v2 < mid));           \
                    if (cnt >= 19) hi_ = mid; else lo_ = mid;                   \
                }                                                               \
                tv[J] = __uint_as_float(hi_ << 16);                             \
                if (lane == 0) ccnt[J][w] = 0;                                  \
                if ((unsigned)v0 < hi_) { int s_ = atomicAdd(&ccnt[J][w], 1); sd16[J][w][s_] = v0; six16[J][w][s_] = i0; } \
                if ((unsigned)v1 < hi_) { int s_ = atomicAdd(&ccnt[J][w], 1); sd16[J][w][s_] = v1; six16[J][w][s_] = i1; } \
                if ((unsigned)v2 < hi_) { int s_ = atomicAdd(&ccnt[J][w], 1); sd16[J][w][s_] = v2; six16[J][w][s_] = i2; } \
            }                                                                   \
        }

    // ---- scan: 2 chunks of 256 cands per segment ----
    for (int ch = 0; ch < 2; ++ch) {
        const int cbase = qbase + (ch << 8);
        const int c0 = cbase + lane, c1 = c0 + 64, c2 = c0 + 128, c3 = c0 + 192;
        float a[QB][4];
        #pragma unroll
        for (int j = 0; j < QB; ++j) { a[j][0]=0.f; a[j][1]=0.f; a[j][2]=0.f; a[j][3]=0.f; }
        #pragma unroll
        for (int k4 = 0; k4 < 16; ++k4) {
            float4 p0 = P4[(size_t)k4*NN + c0];
            float4 p1 = P4[(size_t)k4*NN + c1];
            float4 p2 = P4[(size_t)k4*NN + c2];
            float4 p3 = P4[(size_t)k4*NN + c3];
            #pragma unroll
            for (int j = 0; j < QB; ++j) {
                float4 qv = *(const float4*)&qstage[j][k4 << 2];
                a[j][0] += qv.x*p0.x + qv.y*p0.y + qv.z*p0.z + qv.w*p0.w;
                a[j][1] += qv.x*p1.x + qv.y*p1.y + qv.z*p1.z + qv.w*p1.w;
                a[j][2] += qv.x*p2.x + qv.y*p2.y + qv.z*p2.z + qv.w*p2.w;
                a[j][3] += qv.x*p3.x + qv.y*p3.y + qv.z*p3.z + qv.w*p3.w;
            }
        }
        const float sc0 = sqf[base + c0], sc1 = sqf[base + c1];
        const float sc2 = sqf[base + c2], sc3 = sqf[base + c3];
        #pragma unroll
        for (int j = 0; j < QB; ++j) {
            float d0 = fmaxf(sqq[j] + sc0 - 2.f*a[j][0], 0.f);
            float d1 = fmaxf(sqq[j] + sc1 - 2.f*a[j][1], 0.f);
            float d2 = fmaxf(sqq[j] + sc2 - 2.f*a[j][2], 0.f);
            float d3 = fmaxf(sqq[j] + sc3 - 2.f*a[j][3], 0.f);
            if (c0 == n0 + j) d0 = 1e30f;   // self
            if (c1 == n0 + j) d1 = 1e30f;
            if (c2 == n0 + j) d2 = 1e30f;
            if (c3 == n0 + j) d3 = 1e30f;
            a[j][0] = d0; a[j][1] = d1; a[j][2] = d2; a[j][3] = d3;
        }

        if (ch == 0) {
            #pragma unroll
            for (int j = 0; j < QB; ++j) {
                unsigned lo = 0u, hi = 0x7F80u;
                #pragma unroll 1
                for (int it = 0; it < 16; ++it) {
                    unsigned mid = (lo + hi) >> 1;
                    float fm = __uint_as_float(mid << 16);
                    int cnt = __popcll(__ballot(a[j][0] < fm)) + __popcll(__ballot(a[j][1] < fm))
                            + __popcll(__ballot(a[j][2] < fm)) + __popcll(__ballot(a[j][3] < fm));
                    if (cnt >= 19) hi = mid; else lo = mid;
                }
                tv[j] = __uint_as_float(hi << 16);
            }
        }

        #pragma unroll
        for (int j = 0; j < QB; ++j) {
            APPEND1(j, a[j][0], c0)
            APPEND1(j, a[j][1], c1)
        }
        #pragma unroll
        for (int j = 0; j < QB; ++j) COMPACT1(j)
        #pragma unroll
        for (int j = 0; j < QB; ++j) {
            APPEND1(j, a[j][2], c2)
            APPEND1(j, a[j][3], c3)
        }
        #pragma unroll
        for (int j = 0; j < QB; ++j) COMPACT1(j)
    }

    // ---- final compact to rescue list (bf16 20-quantile, keep < t) ----
    if (lane < QB) rcnt[lane][w] = 0;
    #pragma unroll 1
    for (int j = 0; j < QB; ++j) {
        int cnt0 = ccnt[j][w];
        if (cnt0 > CAP) cnt0 = CAP;
        ushort_t v0 = (lane       < cnt0) ? sd16[j][w][lane]       : (ushort_t)0xFFFF;
        ushort_t v1 = (64 + lane  < cnt0) ? sd16[j][w][64 + lane]  : (ushort_t)0xFFFF;
        ushort_t v2 = (128 + lane < cnt0) ? sd16[j][w][128 + lane] : (ushort_t)0xFFFF;
        ushort_t i0 = (lane       < cnt0) ? six16[j][w][lane]       : (ushort_t)0;
        ushort_t i1 = (64 + lane  < cnt0) ? six16[j][w][64 + lane]  : (ushort_t)0;
        ushort_t i2 = (128 + lane < cnt0) ? six16[j][w][128 + lane] : (ushort_t)0;
        unsigned lo = 0u, hi = 0x7F80u;
        #pragma unroll 1
        for (int it = 0; it < 16; ++it) {
            unsigned mid = (lo + hi) >> 1;
            int cnt = __popcll(__ballot((unsigned)v0 < mid))
                    + __popcll(__ballot((unsigned)v1 < mid))
                    + __popcll(__ballot((unsigned)v2 < mid));
            if (cnt >= 20) hi = mid; else lo = mid;
        }
        if ((unsigned)v0 < hi) { int s = atomicAdd(&rcnt[j][w], 1); if (s < RCAP) rlist[j][w][s] = i0; }
        if ((unsigned)v1 < hi) { int s = atomicAdd(&rcnt[j][w], 1); if (s < RCAP) rlist[j][w][s] = i1; }
        if ((unsigned)v2 < hi) { int s = atomicAdd(&rcnt[j][w], 1); if (s < RCAP) rlist[j][w][s] = i2; }
    }
    __syncthreads();   // sd16/six16 dead -> repurpose POOL

    // ---- build qd64 (f64 query rows) + init umb ----
    for (int i = tid; i < QB*PD; i += 256) {
        int q = i >> 6, p = i & 63;
        size_t g = (size_t)(base + n0 + q)*PD + p;
        qd64[q][p] = (double)nph[g] + (double)npl[g];
    }
    for (int i = tid; i < QB*192; i += 256) {
        umbd[i / 192][i % 192] = 1e300;
        umbi[i] = 0x7fffffff;
    }
    __syncthreads();

    // ---- coalesced f64 rescue: 16-lane groups, 4 candidates per iteration ----
    const int lh = lane & 15, g4 = lane >> 4;
    #pragma unroll 1
    for (int q = 0; q < QB; ++q) {
        int cr = rcnt[q][w]; if (cr > RCAP) cr = RCAP;
        const double qd0 = qd64[q][4*lh+0], qd1 = qd64[q][4*lh+1];
        const double qd2 = qd64[q][4*lh+2], qd3 = qd64[q][4*lh+3];
        const double sq_q = sq64[base + n0 + q];
        for (int s0 = 0; s0 < cr; s0 += 4) {
            const int slot = s0 + g4;
            const bool valid = slot < cr;
            const int cand = valid ? (int)rlist[q][w][slot] : 0;
            const float4 h4 = *(const float4*)(nph + (size_t)(base + cand)*PD + 4*lh);
            const float4 l4 = *(const float4*)(npl + (size_t)(base + cand)*PD + 4*lh);
            double acc = qd0*((double)h4.x + (double)l4.x)
                       + qd1*((double)h4.y + (double)l4.y)
                       + qd2*((double)h4.z + (double)l4.z)
                       + qd3*((double)h4.w + (double)l4.w);
            #pragma unroll
            for (int off = 1; off < 16; off <<= 1) acc += __shfl_xor(acc, off);
            if (valid && lh == 0) {
                umbd[q][w*RCAP + slot] = sq_q + sq64[base + cand] - 2.0*acc;
                umbi[q*192 + w*RCAP + slot] = cand;
            }
        }
    }
    __syncthreads();

    // ---- per-half exact f64 top-16: wave w -> queries 2w, 2w+1; write (d2,idx) to ctx ----
    #pragma unroll 1
    for (int qi = 0; qi < 2; ++qi) {
        const int q = 2*w + qi;
        double ev0 = umbd[q][lane], ev1 = umbd[q][64 + lane], ev2 = umbd[q][128 + lane];
        int ei0 = umbi[q*192 + lane], ei1 = umbi[q*192 + 64 + lane], ei2 = umbi[q*192 + 128 + lane];
        double myd = 1e300; int myi = 0x7fffffff;
        for (int r = 0; r < KNN; ++r) {
            double bv = ev0; int bi = ei0; int bs = 0;
            if (ev1 < bv || (ev1 == bv && ei1 < bi)) { bv = ev1; bi = ei1; bs = 1; }
            if (ev2 < bv || (ev2 == bv && ei2 < bi)) { bv = ev2; bi = ei2; bs = 2; }
            #pragma unroll
            for (int off = 32; off >= 1; off >>= 1) {
                double ov = __shfl_xor(bv, off);
                int    oi = __shfl_xor(bi, off);
                if (ov < bv || (ov == bv && oi < bi)) { bv = ov; bi = oi; }
            }
            if (bs == 0 && ei0 == bi) ev0 = 1e300;
            if (bs == 1 && ei1 == bi) ev1 = 1e300;
            if (bs == 2 && ei2 == bi) ev2 = 1e300;
            if (lane == r) { myd = bv; myi = bi; }
        }
        float* crow = ctx + (size_t)(base + n0 + q)*DIMD;
        if (lane < KNN) {
            ((double*)crow)[half*16 + lane]      = myd;   // floats [0..63]
            ((int*)(crow + 64))[half*16 + lane]  = myi;   // floats [64..95]
        }
    }
    #undef APPEND1
    #undef COMPACT1
}

// ---------------- kernel 3: merge halves (exact top-16 of 32) + weights + context ----------
__global__ __launch_bounds__(256)
void finish_kernel(const float* __restrict__ values, float* __restrict__ ctx)
{
    __shared__ int   s_ix[QB][16];
    __shared__ float s_w[QB][16];
    const int tid  = threadIdx.x;
    const int w    = tid >> 6;
    const int lane = tid & 63;
    const int b    = blockIdx.x >> 9;
    const int n0   = (blockIdx.x & 511) << 3;
    const int base = b * NN;

    {
        const int sub = lane >> 5, sl = lane & 31;
        const int q = 2*w + sub;
        const float* crow = ctx + (size_t)(base + n0 + q)*DIMD;
        double d2 = ((const double*)crow)[sl];
        int    ix = ((const int*)(crow + 64))[sl];
        int rank = 0;
        #pragma unroll 1
        for (int j = 0; j < 32; ++j) {
            double dj = __shfl(d2, j, 32);
            int    ij = __shfl(ix, j, 32);
            rank += (dj < d2) || (dj == d2 && ij < ix);
        }
        double wk = 0.0;
        if (rank < KNN) wk = exp(-0.5 * sqrt(fmax(d2, 1e-12)));
        double ws = wk;
        #pragma unroll
        for (int off = 16; off >= 1; off >>= 1) ws += __shfl_xor(ws, off, 32);
        if (rank < KNN) {
            s_ix[q][rank] = ix;
            s_w[q][rank]  = (float)(wk / (ws + 1e-8));
        }
    }
    __syncthreads();

    // context gather: 8 queries x 512 dims (32 thr/query, 16 dims each); overwrites rows
    {
        const int q  = tid >> 5;
        const int e0 = (tid & 31) << 4;
        const float* V = values + (size_t)base * DIMD;
        float acc2[16] = {};
        for (int k = 0; k < KNN; ++k) {
            int   m  = s_ix[q][k];
            float wg = s_w[q][k];
            const float4* vr = (const float4*)(V + (size_t)m*DIMD + e0);
            #pragma unroll
            for (int t4 = 0; t4 < 4; ++t4) {
                float4 vv = vr[t4];
                acc2[4*t4+0] += wg*vv.x; acc2[4*t4+1] += wg*vv.y;
                acc2[4*t4+2] += wg*vv.z; acc2[4*t4+3] += wg*vv.w;
            }
        }
        float* crow = ctx + (size_t)(base + n0 + q)*DIMD + e0;
        #pragma unroll
        for (int t4 = 0; t4 < 4; ++t4)
            *(float4*)(crow + 4*t4) = make_float4(acc2[4*t4+0], acc2[4*t4+1], acc2[4*t4+2], acc2[4*t4+3]);
    }
}

extern "C" void kernel_launch(void* const* d_in, const int* in_sizes, int n_in,
                              void* d_out, int out_size, void* d_ws, size_t ws_size,
                              hipStream_t stream)
{
    (void)in_sizes; (void)n_in; (void)out_size; (void)ws_size;
    const float* states    = (const float*)d_in[0];
    const float* positions = (const float*)d_in[1];
    const float* W_flow    = (const float*)d_in[2];
    const float* b_flow    = (const float*)d_in[3];
    const float* W_val     = (const float*)d_in[4];
    const float* b_val     = (const float*)d_in[5];

    float* out_ctx = (float*)d_out;                       // [B,N,DIM]
    float* out_np  = out_ctx + (size_t)NB*NN*DIMD;        // [B,N,PD]
    float* out_fl  = out_np  + (size_t)NB*NN*PD;          // [B,N,PD]

    char* ws = (char*)d_ws;
    float*  values_ws = (float*)ws;                                   // 16,777,216 B
    float*  npos_lo   = (float*)(ws + (size_t)16777216);              //  2,097,152 B
    double* sq64      = (double*)(ws + (size_t)18874368);             //     65,536 B
    float*  sqf       = (float*)(ws + (size_t)18939904);              //     32,768 B
    float*  p4t       = (float*)(ws + (size_t)18972672);              //  2,097,152 B
    // total 21,069,824 B (same footprint as rounds 3-19)

    hipLaunchKernelGGL(prep_kernel, dim3(FLOW_BLOCKS + (DIMD/64)*(MROWS/64)), dim3(256), 0, stream,
                       states, positions, W_flow, b_flow, W_val, b_val,
                       out_np, out_fl, npos_lo, p4t, sq64, sqf, values_ws);
    hipLaunchKernelGGL(dist_select, dim3(2048), dim3(256), 0, stream,
                       out_np, npos_lo, (const float4*)p4t, sqf, sq64, out_ctx);
    hipLaunchKernelGGL(finish_kernel, dim3(1024), dim3(256), 0, stream,
                       values_ws, out_ctx);
}

// Round 21
// 315.839 us; speedup vs baseline: 1.2421x; 1.2421x over previous
//
#include <hip/hip_runtime.h>

#define NB 2
#define NN 4096
#define DIMD 512
#define PD 64
#define KNN 16
#define QB 8
#define CAP 192
#define CTRIG 52
#define RCAP 48
#define MROWS (NB*NN)       // 8192
#define FLOW_BLOCKS (MROWS/4)

typedef unsigned short ushort_t;

// ---------------- kernel 1: fused prep = flow (f64, LDS-staged W^T) + values GEMM ----------
__global__ __launch_bounds__(256)
void prep_kernel(const float* __restrict__ states, const float* __restrict__ positions,
                 const float* __restrict__ W_flow, const float* __restrict__ b_flow,
                 const float* __restrict__ W_val, const float* __restrict__ b_val,
                 float* __restrict__ out_np, float* __restrict__ out_fl,
                 float* __restrict__ npos_lo, float* __restrict__ p4t,
                 double* __restrict__ sq64, float* __restrict__ sqf,
                 float* __restrict__ values_ws)
{
    __shared__ __align__(16) unsigned char POOL[24832];
    const int t = threadIdx.x;

    if (blockIdx.x < FLOW_BLOCKS) {
        float (*s_lds)[DIMD] = (float(*)[DIMD])POOL;          // [4][512]  8192 B
        float (*wlds)[65]    = (float(*)[65])(POOL + 8192);   // [64][65] 16640 B
        const int row0 = blockIdx.x * 4;
        const float4* src = (const float4*)(states + (size_t)row0 * DIMD);
        float4* dst = (float4*)&s_lds[0][0];
        dst[t] = src[t];
        dst[t + 256] = src[t + 256];
        const int lr = t >> 6;
        const int p  = t & 63;
        const int row = row0 + lr;
        double a0 = 0.0, a1 = 0.0, a2 = 0.0, a3 = 0.0;
        for (int ph = 0; ph < 8; ++ph) {
            const int d0 = ph << 6;
            __syncthreads();
            #pragma unroll
            for (int i = 0; i < 4; ++i) {
                int slot = t + (i << 8);
                int r = slot >> 4, c = slot & 15;
                float4 wv = *(const float4*)(W_flow + (size_t)r * DIMD + d0 + (c << 2));
                wlds[(c<<2)+0][r] = wv.x;
                wlds[(c<<2)+1][r] = wv.y;
                wlds[(c<<2)+2][r] = wv.z;
                wlds[(c<<2)+3][r] = wv.w;
            }
            __syncthreads();
            #pragma unroll
            for (int sc = 0; sc < 4; ++sc) {
                const int dl = sc << 4;
                float4 s0 = *(const float4*)&s_lds[lr][d0 + dl + 0];
                float4 s1 = *(const float4*)&s_lds[lr][d0 + dl + 4];
                float4 s2 = *(const float4*)&s_lds[lr][d0 + dl + 8];
                float4 s3 = *(const float4*)&s_lds[lr][d0 + dl + 12];
                a0 += (double)s0.x * (double)wlds[dl+ 0][p];
                a1 += (double)s0.y * (double)wlds[dl+ 1][p];
                a2 += (double)s0.z * (double)wlds[dl+ 2][p];
                a3 += (double)s0.w * (double)wlds[dl+ 3][p];
                a0 += (double)s1.x * (double)wlds[dl+ 4][p];
                a1 += (double)s1.y * (double)wlds[dl+ 5][p];
                a2 += (double)s1.z * (double)wlds[dl+ 6][p];
                a3 += (double)s1.w * (double)wlds[dl+ 7][p];
                a0 += (double)s2.x * (double)wlds[dl+ 8][p];
                a1 += (double)s2.y * (double)wlds[dl+ 9][p];
                a2 += (double)s2.z * (double)wlds[dl+10][p];
                a3 += (double)s2.w * (double)wlds[dl+11][p];
                a0 += (double)s3.x * (double)wlds[dl+12][p];
                a1 += (double)s3.y * (double)wlds[dl+13][p];
                a2 += (double)s3.z * (double)wlds[dl+14][p];
                a3 += (double)s3.w * (double)wlds[dl+15][p];
            }
        }
        double acc = ((a0 + a1) + (a2 + a3)) + (double)b_flow[p];
        const size_t g = (size_t)row * PD + p;
        double np_ = (double)positions[g] + 0.1 * acc;
        float hi = (float)np_;
        float lo = (float)(np_ - (double)hi);
        out_fl[g]   = (float)acc;
        out_np[g]   = hi;
        npos_lo[g]  = lo;
        const int bb = row >> 12, n = row & (NN - 1);
        p4t[(((size_t)bb*16 + (p >> 2))*NN + n)*4 + (p & 3)] = hi;
        double s2 = np_ * np_;
        #pragma unroll
        for (int off = 32; off >= 1; off >>= 1) s2 += __shfl_xor(s2, off);
        if (p == 0) { sq64[row] = s2; sqf[row] = (float)s2; }
    } else {
        float (*As)[68] = (float(*)[68])POOL;              // 4352 B
        float (*Bs)[68] = (float(*)[68])(POOL + 4352);     // 4352 B
        const int idx = blockIdx.x - FLOW_BLOCKS;
        const int bn = idx & 7, bm = idx >> 3;
        const int lr  = t >> 2;
        const int lc4 = (t & 3) << 2;
        const int cr = (t >> 4) << 2;
        const int cc = (t & 15) << 2;
        float acc[4][4] = {};
        for (int k0 = 0; k0 < DIMD; k0 += 16) {
            float4 av = *(const float4*)(states + (size_t)(bm*64 + lr)*DIMD + k0 + lc4);
            float4 wv = *(const float4*)(W_val  + (size_t)(bn*64 + lr)*DIMD + k0 + lc4);
            __syncthreads();
            As[lc4+0][lr] = av.x; As[lc4+1][lr] = av.y; As[lc4+2][lr] = av.z; As[lc4+3][lr] = av.w;
            Bs[lc4+0][lr] = wv.x; Bs[lc4+1][lr] = wv.y; Bs[lc4+2][lr] = wv.z; Bs[lc4+3][lr] = wv.w;
            __syncthreads();
            #pragma unroll
            for (int kk = 0; kk < 16; ++kk) {
                float4 a  = *(const float4*)&As[kk][cr];
                float4 b4 = *(const float4*)&Bs[kk][cc];
                acc[0][0] += a.x*b4.x; acc[0][1] += a.x*b4.y; acc[0][2] += a.x*b4.z; acc[0][3] += a.x*b4.w;
                acc[1][0] += a.y*b4.x; acc[1][1] += a.y*b4.y; acc[1][2] += a.y*b4.z; acc[1][3] += a.y*b4.w;
                acc[2][0] += a.z*b4.x; acc[2][1] += a.z*b4.y; acc[2][2] += a.z*b4.z; acc[2][3] += a.z*b4.w;
                acc[3][0] += a.w*b4.x; acc[3][1] += a.w*b4.y; acc[3][2] += a.w*b4.z; acc[3][3] += a.w*b4.w;
            }
        }
        const int colb = bn*64 + cc;
        float4 bb = *(const float4*)(b_val + colb);
        #pragma unroll
        for (int i = 0; i < 4; ++i) {
            float4 o;
            o.x = acc[i][0] + bb.x;
            o.y = acc[i][1] + bb.y;
            o.z = acc[i][2] + bb.z;
            o.w = acc[i][3] + bb.w;
            *(float4*)(values_ws + (size_t)(bm*64 + cr + i)*DIMD + colb) = o;
        }
    }
}

// ---------------- kernel 2: 8q/block scan (4-stream chunks) + f64 rescue + context ---------
__global__ __launch_bounds__(256, 4)
void dist_kernel(const float* __restrict__ nph, const float* __restrict__ npl,
                 const float4* __restrict__ p4t, const float* __restrict__ sqf,
                 const double* __restrict__ sq64, const float* __restrict__ values,
                 float* __restrict__ ctx)
{
    __shared__ __align__(16) unsigned char POOL[24576];
    __shared__ float    qstage[QB][68];
    __shared__ ushort_t rlist[QB][4][RCAP];
    __shared__ int      ccnt[QB][4];
    __shared__ int      rcnt[QB][4];

    // phase 1 aliases
    ushort_t (*sd16)[4][CAP]  = (ushort_t(*)[4][CAP])POOL;               // 12288
    ushort_t (*six16)[4][CAP] = (ushort_t(*)[4][CAP])(POOL + 12288);     // 12288
    // phase 2 aliases
    double (*umbd)[192] = (double(*)[192])POOL;                          // 12288
    int*    umbi        = (int*)(POOL + 12288);                          //  6144
    double (*qd64)[66]  = (double(*)[66])(POOL + 18432);                 //  4224
    int*    fin_ix      = (int*)(POOL + 22656);                          //   512
    float*  fin_w       = (float*)(POOL + 23168);                        //   512

    const int tid  = threadIdx.x;
    const int w    = tid >> 6;        // quarter id
    const int lane = tid & 63;
    const int b    = blockIdx.x >> 9;
    const int n0   = (blockIdx.x & 511) << 3;
    const int base = b * NN;

    if (tid < 32) ccnt[tid >> 2][tid & 3] = 0;
    if (tid < 128) {
        int row = tid >> 4, c4 = (tid & 15) << 2;
        *(float4*)&qstage[row][c4] = *(const float4*)(nph + (size_t)(base + n0 + row)*PD + c4);
    }
    __syncthreads();

    float sqq[QB], tv[QB];
    #pragma unroll
    for (int j = 0; j < QB; ++j) { sqq[j] = sqf[base + n0 + j]; tv[j] = 1e30f; }

    const float4* P4 = p4t + (size_t)b * 16 * NN;
    const int qbase = w << 10;

    #define APPEND1(J, DV, CI)                                                  \
        if ((DV) < tv[J]) {                                                     \
            int s_ = atomicAdd(&ccnt[J][w], 1);                                 \
            if (s_ < CAP) {                                                     \
                sd16[J][w][s_]  = (ushort_t)(__float_as_uint(DV) >> 16);        \
                six16[J][w][s_] = (ushort_t)(CI);                               \
            }                                                                   \
        }

    #define COMPACT1(J)                                                         \
        {                                                                       \
            int cnt0 = ccnt[J][w];                                              \
            if (cnt0 > CTRIG) {                                                 \
                if (cnt0 > CAP) cnt0 = CAP;                                     \
                ushort_t v0 = (lane       < cnt0) ? sd16[J][w][lane]       : (ushort_t)0xFFFF; \
                ushort_t v1 = (64 + lane  < cnt0) ? sd16[J][w][64 + lane]  : (ushort_t)0xFFFF; \
                ushort_t v2 = (128 + lane < cnt0) ? sd16[J][w][128 + lane] : (ushort_t)0xFFFF; \
                ushort_t i0 = (lane       < cnt0) ? six16[J][w][lane]       : (ushort_t)0; \
                ushort_t i1 = (64 + lane  < cnt0) ? six16[J][w][64 + lane]  : (ushort_t)0; \
                ushort_t i2 = (128 + lane < cnt0) ? six16[J][w][128 + lane] : (ushort_t)0; \
                unsigned lo_ = 0u, hi_ = 0x7F80u;                               \
                _Pragma("unroll 1")                                             \
                for (int it = 0; it < 16; ++it) {                               \
                    unsigned mid = (lo_ + hi_) >> 1;                            \
                    int cnt = __popcll(__ballot((unsigned)v0 < mid))            \
                            + __popcll(__ballot((unsigned)v1 < mid))            \
                            + __popcll(__ballot((unsigned)v2 < mid));           \
                    if (cnt >= 19) hi_ = mid; else lo_ = mid;                   \
                }                                                               \
                tv[J] = __uint_as_float(hi_ << 16);                             \
                if (lane == 0) ccnt[J][w] = 0;                                  \
                if ((unsigned)v0 < hi_) { int s_ = atomicAdd(&ccnt[J][w], 1); sd16[J][w][s_] = v0; six16[J][w][s_] = i0; } \
                if ((unsigned)v1 < hi_) { int s_ = atomicAdd(&ccnt[J][w], 1); sd16[J][w][s_] = v1; six16[J][w][s_] = i1; } \
                if ((unsigned)v2 < hi_) { int s_ = atomicAdd(&ccnt[J][w], 1); sd16[J][w][s_] = v2; six16[J][w][s_] = i2; } \
            }                                                                   \
        }

    // ---- scan: 4 chunks of 256 cands per quarter ----
    for (int ch = 0; ch < 4; ++ch) {
        const int cbase = qbase + (ch << 8);
        const int c0 = cbase + lane, c1 = c0 + 64, c2 = c0 + 128, c3 = c0 + 192;
        float a[QB][4];
        #pragma unroll
        for (int j = 0; j < QB; ++j) { a[j][0]=0.f; a[j][1]=0.f; a[j][2]=0.f; a[j][3]=0.f; }
        #pragma unroll
        for (int k4 = 0; k4 < 16; ++k4) {
            float4 p0 = P4[(size_t)k4*NN + c0];
            float4 p1 = P4[(size_t)k4*NN + c1];
            float4 p2 = P4[(size_t)k4*NN + c2];
            float4 p3 = P4[(size_t)k4*NN + c3];
            #pragma unroll
            for (int j = 0; j < QB; ++j) {
                float4 qv = *(const float4*)&qstage[j][k4 << 2];
                a[j][0] += qv.x*p0.x + qv.y*p0.y + qv.z*p0.z + qv.w*p0.w;
                a[j][1] += qv.x*p1.x + qv.y*p1.y + qv.z*p1.z + qv.w*p1.w;
                a[j][2] += qv.x*p2.x + qv.y*p2.y + qv.z*p2.z + qv.w*p2.w;
                a[j][3] += qv.x*p3.x + qv.y*p3.y + qv.z*p3.z + qv.w*p3.w;
            }
        }
        const float sc0 = sqf[base + c0], sc1 = sqf[base + c1];
        const float sc2 = sqf[base + c2], sc3 = sqf[base + c3];
        #pragma unroll
        for (int j = 0; j < QB; ++j) {
            float d0 = fmaxf(sqq[j] + sc0 - 2.f*a[j][0], 0.f);
            float d1 = fmaxf(sqq[j] + sc1 - 2.f*a[j][1], 0.f);
            float d2 = fmaxf(sqq[j] + sc2 - 2.f*a[j][2], 0.f);
            float d3 = fmaxf(sqq[j] + sc3 - 2.f*a[j][3], 0.f);
            if (c0 == n0 + j) d0 = 1e30f;   // self
            if (c1 == n0 + j) d1 = 1e30f;
            if (c2 == n0 + j) d2 = 1e30f;
            if (c3 == n0 + j) d3 = 1e30f;
            a[j][0] = d0; a[j][1] = d1; a[j][2] = d2; a[j][3] = d3;
        }

        if (ch == 0) {
            // t0: smallest bf16 boundary with >=19 of this chunk's 256 d2 strictly below
            #pragma unroll
            for (int j = 0; j < QB; ++j) {
                unsigned lo = 0u, hi = 0x7F80u;
                #pragma unroll 1
                for (int it = 0; it < 16; ++it) {
                    unsigned mid = (lo + hi) >> 1;
                    float fm = __uint_as_float(mid << 16);
                    int cnt = __popcll(__ballot(a[j][0] < fm)) + __popcll(__ballot(a[j][1] < fm))
                            + __popcll(__ballot(a[j][2] < fm)) + __popcll(__ballot(a[j][3] < fm));
                    if (cnt >= 19) hi = mid; else lo = mid;
                }
                tv[j] = __uint_as_float(hi << 16);
            }
        }

        // half A (streams 0,1), compact-check; half B (streams 2,3), compact-check
        #pragma unroll
        for (int j = 0; j < QB; ++j) {
            APPEND1(j, a[j][0], c0)
            APPEND1(j, a[j][1], c1)
        }
        #pragma unroll
        for (int j = 0; j < QB; ++j) COMPACT1(j)
        #pragma unroll
        for (int j = 0; j < QB; ++j) {
            APPEND1(j, a[j][2], c2)
            APPEND1(j, a[j][3], c3)
        }
        #pragma unroll
        for (int j = 0; j < QB; ++j) COMPACT1(j)
    }

    // ---- final compact to rescue list (bf16 20-quantile, keep < t) ----
    if (lane < QB) rcnt[lane][w] = 0;
    #pragma unroll 1
    for (int j = 0; j < QB; ++j) {
        int cnt0 = ccnt[j][w];
        if (cnt0 > CAP) cnt0 = CAP;
        ushort_t v0 = (lane       < cnt0) ? sd16[j][w][lane]       : (ushort_t)0xFFFF;
        ushort_t v1 = (64 + lane  < cnt0) ? sd16[j][w][64 + lane]  : (ushort_t)0xFFFF;
        ushort_t v2 = (128 + lane < cnt0) ? sd16[j][w][128 + lane] : (ushort_t)0xFFFF;
        ushort_t i0 = (lane       < cnt0) ? six16[j][w][lane]       : (ushort_t)0;
        ushort_t i1 = (64 + lane  < cnt0) ? six16[j][w][64 + lane]  : (ushort_t)0;
        ushort_t i2 = (128 + lane < cnt0) ? six16[j][w][128 + lane] : (ushort_t)0;
        unsigned lo = 0u, hi = 0x7F80u;
        #pragma unroll 1
        for (int it = 0; it < 16; ++it) {
            unsigned mid = (lo + hi) >> 1;
            int cnt = __popcll(__ballot((unsigned)v0 < mid))
                    + __popcll(__ballot((unsigned)v1 < mid))
                    + __popcll(__ballot((unsigned)v2 < mid));
            if (cnt >= 20) hi = mid; else lo = mid;
        }
        if ((unsigned)v0 < hi) { int s = atomicAdd(&rcnt[j][w], 1); if (s < RCAP) rlist[j][w][s] = i0; }
        if ((unsigned)v1 < hi) { int s = atomicAdd(&rcnt[j][w], 1); if (s < RCAP) rlist[j][w][s] = i1; }
        if ((unsigned)v2 < hi) { int s = atomicAdd(&rcnt[j][w], 1); if (s < RCAP) rlist[j][w][s] = i2; }
    }
    __syncthreads();   // sd16/six16 dead -> repurpose POOL

    // ---- build qd64 (f64 query rows) + init umb ----
    for (int i = tid; i < QB*PD; i += 256) {
        int q = i >> 6, p = i & 63;
        size_t g = (size_t)(base + n0 + q)*PD + p;
        qd64[q][p] = (double)nph[g] + (double)npl[g];
    }
    for (int i = tid; i < QB*192; i += 256) {
        umbd[i / 192][i % 192] = 1e300;
        umbi[i] = 0x7fffffff;
    }
    __syncthreads();

    // ---- coalesced f64 rescue: 16-lane groups, 4 candidates per iteration ----
    const int lh = lane & 15, g4 = lane >> 4;
    #pragma unroll 1
    for (int q = 0; q < QB; ++q) {
        int cr = rcnt[q][w]; if (cr > RCAP) cr = RCAP;
        const double qd0 = qd64[q][4*lh+0], qd1 = qd64[q][4*lh+1];
        const double qd2 = qd64[q][4*lh+2], qd3 = qd64[q][4*lh+3];
        const double sq_q = sq64[base + n0 + q];
        for (int s0 = 0; s0 < cr; s0 += 4) {
            const int slot = s0 + g4;
            const bool valid = slot < cr;
            const int cand = valid ? (int)rlist[q][w][slot] : 0;
            const float4 h4 = *(const float4*)(nph + (size_t)(base + cand)*PD + 4*lh);
            const float4 l4 = *(const float4*)(npl + (size_t)(base + cand)*PD + 4*lh);
            double acc = qd0*((double)h4.x + (double)l4.x)
                       + qd1*((double)h4.y + (double)l4.y)
                       + qd2*((double)h4.z + (double)l4.z)
                       + qd3*((double)h4.w + (double)l4.w);
            #pragma unroll
            for (int off = 1; off < 16; off <<= 1) acc += __shfl_xor(acc, off);
            if (valid && lh == 0) {
                umbd[q][w*RCAP + slot] = sq_q + sq64[base + cand] - 2.0*acc;
                umbi[q*192 + w*RCAP + slot] = cand;
            }
        }
    }
    __syncthreads();

    // ---- exact f64 top-16 + weights: wave w -> queries 2w, 2w+1 (union <= 192) ----
    #pragma unroll 1
    for (int qi = 0; qi < 2; ++qi) {
        const int q = 2*w + qi;
        double ev0 = umbd[q][lane], ev1 = umbd[q][64 + lane], ev2 = umbd[q][128 + lane];
        int ei0 = umbi[q*192 + lane], ei1 = umbi[q*192 + 64 + lane], ei2 = umbi[q*192 + 128 + lane];
        double wsum = 0.0, mywk = 0.0;
        for (int r = 0; r < KNN; ++r) {
            double bv = ev0; int bi = ei0; int bs = 0;
            if (ev1 < bv || (ev1 == bv && ei1 < bi)) { bv = ev1; bi = ei1; bs = 1; }
            if (ev2 < bv || (ev2 == bv && ei2 < bi)) { bv = ev2; bi = ei2; bs = 2; }
            #pragma unroll
            for (int off = 32; off >= 1; off >>= 1) {
                double ov = __shfl_xor(bv, off);
                int    oi = __shfl_xor(bi, off);
                if (ov < bv || (ov == bv && oi < bi)) { bv = ov; bi = oi; }
            }
            if (bs == 0 && ei0 == bi) ev0 = 1e300;
            if (bs == 1 && ei1 == bi) ev1 = 1e300;
            if (bs == 2 && ei2 == bi) ev2 = 1e300;
            double wk = exp(-0.5 * sqrt(fmax(bv, 1e-12)));
            wsum += wk;
            if (lane == r) mywk = wk;
            if (lane == 0) fin_ix[q*16 + r] = bi;
        }
        if (lane < KNN) fin_w[q*16 + lane] = (float)(mywk / (wsum + 1e-8));
    }
    __syncthreads();

    // ---- context: 8 queries x 512 dims (32 thr/query, 16 dims each) ----
    {
        const int q  = tid >> 5;
        const int e0 = (tid & 31) << 4;
        const float* V = values + (size_t)base * DIMD;
        float acc2[16] = {};
        for (int k = 0; k < KNN; ++k) {
            int   m  = fin_ix[q*16 + k];
            float wg = fin_w[q*16 + k];
            const float4* vr = (const float4*)(V + (size_t)m*DIMD + e0);
            #pragma unroll
            for (int t4 = 0; t4 < 4; ++t4) {
                float4 vv = vr[t4];
                acc2[4*t4+0] += wg*vv.x; acc2[4*t4+1] += wg*vv.y;
                acc2[4*t4+2] += wg*vv.z; acc2[4*t4+3] += wg*vv.w;
            }
        }
        float* crow = ctx + (size_t)(base + n0 + q)*DIMD + e0;
        #pragma unroll
        for (int t4 = 0; t4 < 4; ++t4)
            *(float4*)(crow + 4*t4) = make_float4(acc2[4*t4+0], acc2[4*t4+1], acc2[4*t4+2], acc2[4*t4+3]);
    }
    #undef APPEND1
    #undef COMPACT1
}

extern "C" void kernel_launch(void* const* d_in, const int* in_sizes, int n_in,
                              void* d_out, int out_size, void* d_ws, size_t ws_size,
                              hipStream_t stream)
{
    (void)in_sizes; (void)n_in; (void)out_size; (void)ws_size;
    const float* states    = (const float*)d_in[0];
    const float* positions = (const float*)d_in[1];
    const float* W_flow    = (const float*)d_in[2];
    const float* b_flow    = (const float*)d_in[3];
    const float* W_val     = (const float*)d_in[4];
    const float* b_val     = (const float*)d_in[5];

    float* out_ctx = (float*)d_out;                       // [B,N,DIM]
    float* out_np  = out_ctx + (size_t)NB*NN*DIMD;        // [B,N,PD]
    float* out_fl  = out_np  + (size_t)NB*NN*PD;          // [B,N,PD]

    char* ws = (char*)d_ws;
    float*  values_ws = (float*)ws;                                   // 16,777,216 B
    float*  npos_lo   = (float*)(ws + (size_t)16777216);              //  2,097,152 B
    double* sq64      = (double*)(ws + (size_t)18874368);             //     65,536 B
    float*  sqf       = (float*)(ws + (size_t)18939904);              //     32,768 B
    float*  p4t       = (float*)(ws + (size_t)18972672);              //  2,097,152 B
    // total 21,069,824 B (same footprint as rounds 3-20)

    hipLaunchKernelGGL(prep_kernel, dim3(FLOW_BLOCKS + (DIMD/64)*(MROWS/64)), dim3(256), 0, stream,
                       states, positions, W_flow, b_flow, W_val, b_val,
                       out_np, out_fl, npos_lo, p4t, sq64, sqf, values_ws);
    hipLaunchKernelGGL(dist_kernel, dim3(NB*512), dim3(256), 0, stream,
                       out_np, npos_lo, (const float4*)p4t, sqf, sq64, values_ws, out_ctx);
}